// Round 9
// baseline (250.560 us; speedup 1.0000x reference)
//
#include <hip/hip_runtime.h>
#include <hip/hip_bf16.h>
#include <math.h>

// NT-Xent loss, fully fused single persistent kernel. N=8192 rows, D=256.
// History (totals): R3 131.9 | R5 130.0 | R6 125.0 | R7 124.2 | R9 123.8 |
//   R10 129.9 | R11 191.3 (LDS atomicAdd = CAS loop + spill: REVERTED).
// Accounting: per iter = fill 44us (harness re-poison) + k_norm 3 + k_sim
//   ~41.5 + k_nll 3.5 + ~32us of inter-dispatch gaps. Five rounds of k_sim
//   scheduling surgery moved the total <=1us; the launch gaps are the
//   cheapest big lever left.
// R12: ONE kernel, grid 512 = exactly 2 blocks/CU x 256 CU @ (256,2)
//   (LDS 16.6KB, VGPR ~80 -> co-residency guaranteed by launch_bounds).
//   Phase0: each block normalizes 16 rows fp32->bf16, zeros its sumexp
//   slice; grid barrier #1 (flag array, device-scope atomics + threadfence
//   for cross-XCD L2 coherence, G16). Phase1: R7's k_sim VERBATIM (best
//   measured: 512 balanced persistent blocks, symmetry, per-strip csum
//   global atomics). Grid barrier #2. Phase2: nll for the block's 16 rows
//   + mean via atomicAdd. Flag poison-safety: flg2 zeroed in phase0, flg1
//   zeroed at end (covers both re-poison and no-repoison harness modes).
#define N_ROWS 8192
#define D_DIM  256
#define HALF_N 4096
#define NBLK   512
#define INV_T      14.285714285714286f      // 1/0.07
#define SCALE_LOG2 20.609929155556620f      // log2(e)/0.07
#define NEG_SCALE  -20.609929155556620f
#define EPSV   1e-8f
#define SENT   0x5AFEC0DEu

typedef __attribute__((ext_vector_type(8))) short bf16x8;   // 8 bf16 = 4 VGPR
typedef __attribute__((ext_vector_type(4))) float f32x4;

#define AS1 __attribute__((address_space(1)))
#define AS3 __attribute__((address_space(3)))

__device__ inline unsigned short f2bf(float x) {
    unsigned int u = __float_as_uint(x);
    unsigned int r = (u + 0x7fffu + ((u >> 16) & 1u)) >> 16;   // RNE
    return (unsigned short)r;
}

__global__ __launch_bounds__(256, 2) void k_all(const float* __restrict__ feat,
                                                unsigned short* __restrict__ fbf,
                                                float* __restrict__ sumexp,
                                                unsigned int* __restrict__ flg1,
                                                unsigned int* __restrict__ flg2,
                                                float* __restrict__ out) {
    __shared__ __align__(16) char Bs[16384];
    __shared__ float red[4];
    const int tid  = threadIdx.x;
    const int b    = blockIdx.x;
    const int lane = tid & 63;
    const int w    = tid >> 6;
    const int q    = lane >> 4, l15 = lane & 15;

    // ================= phase 0: normalize 16 rows, zero accumulators ======
    if (tid == 0)
        __hip_atomic_store(&flg2[b], 0u, __ATOMIC_RELAXED, __HIP_MEMORY_SCOPE_AGENT);
    #pragma unroll
    for (int r = 0; r < 4; ++r) {
        const int row = b * 16 + w * 4 + r;
        const float4 v = ((const float4*)(feat + row * D_DIM))[lane];
        float ss = v.x*v.x + v.y*v.y + v.z*v.z + v.w*v.w;
        #pragma unroll
        for (int off = 32; off; off >>= 1) ss += __shfl_xor(ss, off);
        const float sc = 1.f / fmaxf(sqrtf(ss), EPSV);
        ushort4 o;
        o.x = f2bf(v.x * sc); o.y = f2bf(v.y * sc);
        o.z = f2bf(v.z * sc); o.w = f2bf(v.w * sc);
        ((ushort4*)(fbf + row * D_DIM))[lane] = o;
    }
    if (tid < 16) sumexp[b * 16 + tid] = 0.f;
    if (b == 0 && tid == 0) out[0] = 0.f;

    // ---- grid barrier #1: all rows normalized, sumexp zeroed -------------
    __syncthreads();
    __threadfence();                                   // agent release (wb L2)
    if (tid == 0)
        __hip_atomic_store(&flg1[b], SENT, __ATOMIC_RELEASE, __HIP_MEMORY_SCOPE_AGENT);
    for (int j = tid; j < NBLK; j += 256)
        while (__hip_atomic_load(&flg1[j], __ATOMIC_RELAXED, __HIP_MEMORY_SCOPE_AGENT) != SENT)
            __builtin_amdgcn_s_sleep(2);
    __syncthreads();
    __threadfence();                                   // agent acquire (inv L2)

    // ================= phase 1: R7 k_sim body (verbatim) ==================
    {
    int g          = (33 * b) >> 2;                   // first strip
    const int gEnd = (33 * (b + 1)) >> 2;             // one past last

    const int tt0 = g >> 3;
    int rt = (int)((sqrtf(8.f * (float)tt0 + 1.f) - 1.f) * 0.5f);
    while ((rt + 1) * (rt + 2) / 2 <= tt0) ++rt;
    while (rt * (rt + 1) / 2 > tt0) --rt;
    int cs = tt0 - rt * (rt + 1) / 2;
    int jt = g & 7;

#define STAGE(colRow0) do {                                                   \
        const char* Bg_ = (const char*)fbf + (size_t)(colRow0) * 512;         \
        _Pragma("unroll")                                                     \
        for (int i_ = 0; i_ < 4; ++i_) {                                      \
            const int idx_ = i_ * 256 + tid;                                  \
            const int col_ = idx_ >> 5;                                       \
            const int cir_ = idx_ & 31;                                       \
            __builtin_amdgcn_global_load_lds(                                 \
                (const AS1 void*)(Bg_ + col_ * 512 + ((cir_ ^ (col_ & 7)) << 4)), \
                (AS3 void*)(Bs + idx_ * 16), 16, 0, 0);                       \
        }                                                                     \
    } while (0)

    bf16x8 afrag[8][4];
#define LOAD_A(rt_) do {                                                      \
        const int rowBase_ = (rt_) * 256 + w * 64;                            \
        _Pragma("unroll")                                                     \
        for (int t_ = 0; t_ < 8; ++t_)                                        \
            _Pragma("unroll")                                                 \
            for (int ri_ = 0; ri_ < 4; ++ri_)                                 \
                afrag[t_][ri_] = *(const bf16x8*)(fbf                         \
                    + (rowBase_ + ri_*16 + l15) * D_DIM + t_*32 + q*8);       \
    } while (0)

    float rsum[4][4];
#define ZERO_RSUM() do {                                                      \
        _Pragma("unroll")                                                     \
        for (int ri_ = 0; ri_ < 4; ++ri_)                                     \
            _Pragma("unroll")                                                 \
            for (int r_ = 0; r_ < 4; ++r_) rsum[ri_][r_] = 0.f;               \
    } while (0)

#define FLUSH_RSUM(rt_) do {                                                  \
        const int rowBase_ = (rt_) * 256 + w * 64;                            \
        _Pragma("unroll")                                                     \
        for (int ri_ = 0; ri_ < 4; ++ri_)                                     \
            _Pragma("unroll")                                                 \
            for (int r_ = 0; r_ < 4; ++r_) {                                  \
                float s_ = rsum[ri_][r_];                                     \
                s_ += __shfl_xor(s_, 1);                                      \
                s_ += __shfl_xor(s_, 2);                                      \
                s_ += __shfl_xor(s_, 4);                                      \
                s_ += __shfl_xor(s_, 8);                                      \
                if (l15 == 0)                                                 \
                    atomicAdd(&sumexp[rowBase_ + ri_ * 16 + q * 4 + r_], s_); \
            }                                                                 \
    } while (0)

    STAGE(cs * 256 + jt * 32);
    LOAD_A(rt);
    ZERO_RSUM();

    while (true) {
        const int colBase = cs * 256 + jt * 32;
        const bool isDiag = (rt == cs);
        const int rowBase = rt * 256 + w * 64;

        __syncthreads();                           // DMA of strip g drained

        f32x4 acc[4][2];
        #pragma unroll
        for (int ri = 0; ri < 4; ++ri)
            #pragma unroll
            for (int ci = 0; ci < 2; ++ci) acc[ri][ci] = (f32x4){0.f, 0.f, 0.f, 0.f};

        #pragma unroll
        for (int t = 0; t < 8; ++t) {
            bf16x8 bfrag[2];
            #pragma unroll
            for (int ci = 0; ci < 2; ++ci) {
                const int c   = ci * 16 + l15;     // local col 0..31
                const int cir = t * 4 + q;         // k-chunk
                bfrag[ci] = *(const bf16x8*)(Bs + c * 512 + ((cir ^ (c & 7)) << 4));
            }
            #pragma unroll
            for (int ri = 0; ri < 4; ++ri)
                #pragma unroll
                for (int ci = 0; ci < 2; ++ci)
                    acc[ri][ci] = __builtin_amdgcn_mfma_f32_16x16x32_bf16(
                        afrag[t][ri], bfrag[ci], acc[ri][ci], 0, 0, 0);
        }

        const bool more = (g + 1 < gEnd);
        int nrt = rt, ncs = cs, njt = jt + 1;
        if (njt == 8) {
            njt = 0; ncs = cs + 1;
            if (ncs > rt) { nrt = rt + 1; ncs = 0; }
        }

        if (more) {
            __syncthreads();                       // all waves done reading Bs
            STAGE(ncs * 256 + njt * 32);
            if (njt == 0) LOAD_A(nrt);             // reload hides under exp
        }

        if (isDiag) {
            #pragma unroll
            for (int ri = 0; ri < 4; ++ri) {
                const int trow = rowBase + ri * 16;
                #pragma unroll
                for (int ci = 0; ci < 2; ++ci) {
                    const int tcol = colBase + ci * 16;
                    if (trow == tcol) {            // diagonal 16x16 tile
                        #pragma unroll
                        for (int r = 0; r < 4; ++r) {
                            const float e = __builtin_amdgcn_exp2f(
                                __builtin_fmaf(acc[ri][ci][r], SCALE_LOG2, NEG_SCALE));
                            rsum[ri][r] += (q * 4 + r == l15) ? 0.f : e;
                        }
                    } else {
                        #pragma unroll
                        for (int r = 0; r < 4; ++r)
                            rsum[ri][r] += __builtin_amdgcn_exp2f(
                                __builtin_fmaf(acc[ri][ci][r], SCALE_LOG2, NEG_SCALE));
                    }
                }
            }
        } else {
            float csum0 = 0.f, csum1 = 0.f;
            #pragma unroll
            for (int ri = 0; ri < 4; ++ri) {
                #pragma unroll
                for (int r = 0; r < 4; ++r) {
                    const float e0 = __builtin_amdgcn_exp2f(
                        __builtin_fmaf(acc[ri][0][r], SCALE_LOG2, NEG_SCALE));
                    const float e1 = __builtin_amdgcn_exp2f(
                        __builtin_fmaf(acc[ri][1][r], SCALE_LOG2, NEG_SCALE));
                    rsum[ri][r] += e0 + e1;
                    csum0 += e0;
                    csum1 += e1;
                }
            }
            csum0 += __shfl_xor(csum0, 16); csum0 += __shfl_xor(csum0, 32);
            csum1 += __shfl_xor(csum1, 16); csum1 += __shfl_xor(csum1, 32);
            if (q == 0)      atomicAdd(&sumexp[colBase      + l15], csum0);
            else if (q == 1) atomicAdd(&sumexp[colBase + 16 + l15], csum1);
        }

        if (!more) break;
        if (njt == 0) {                            // crossed a tile boundary
            FLUSH_RSUM(rt);
            ZERO_RSUM();
        }
        rt = nrt; cs = ncs; jt = njt; ++g;
    }

    FLUSH_RSUM(rt);
#undef STAGE
#undef LOAD_A
#undef ZERO_RSUM
#undef FLUSH_RSUM
    }

    // ---- grid barrier #2: sumexp complete ---------------------------------
    __threadfence();
    if (tid == 0)
        __hip_atomic_store(&flg2[b], SENT, __ATOMIC_RELEASE, __HIP_MEMORY_SCOPE_AGENT);
    for (int j = tid; j < NBLK; j += 256)
        while (__hip_atomic_load(&flg2[j], __ATOMIC_RELAXED, __HIP_MEMORY_SCOPE_AGENT) != SENT)
            __builtin_amdgcn_s_sleep(2);
    __syncthreads();
    __threadfence();

    // ================= phase 2: nll for this block's 16 rows ==============
    float wsum = 0.f;
    #pragma unroll
    for (int r = 0; r < 4; ++r) {
        const int i  = b * 16 + w * 4 + r;
        const int pc = (i + HALF_N) & (N_ROWS - 1);
        const float4 a = ((const float4*)(feat + i  * D_DIM))[lane];
        const float4 c = ((const float4*)(feat + pc * D_DIM))[lane];
        float dab = a.x*c.x + a.y*c.y + a.z*c.z + a.w*c.w;
        float daa = a.x*a.x + a.y*a.y + a.z*a.z + a.w*a.w;
        float dbb = c.x*c.x + c.y*c.y + c.z*c.z + c.w*c.w;
        #pragma unroll
        for (int off = 32; off; off >>= 1) {
            dab += __shfl_xor(dab, off);
            daa += __shfl_xor(daa, off);
            dbb += __shfl_xor(dbb, off);
        }
        if (lane == 0) {
            const float se = __hip_atomic_load(&sumexp[i], __ATOMIC_RELAXED,
                                               __HIP_MEMORY_SCOPE_AGENT);
            const float pos = dab / (fmaxf(sqrtf(daa), EPSV) * fmaxf(sqrtf(dbb), EPSV));
            wsum += INV_T + logf(se) - pos * INV_T;
        }
    }
    if (lane == 0) red[w] = wsum;
    __syncthreads();
    if (tid == 0) {
        atomicAdd(out, (red[0] + red[1] + red[2] + red[3]) * (1.f / N_ROWS));
        // reset barrier-1 flag for the next iteration (safe: everyone passed
        // barrier 2, which implies barrier 1 fully observed)
        __hip_atomic_store(&flg1[b], 0u, __ATOMIC_RELAXED, __HIP_MEMORY_SCOPE_AGENT);
    }
}

extern "C" void kernel_launch(void* const* d_in, const int* in_sizes, int n_in,
                              void* d_out, int out_size, void* d_ws, size_t ws_size,
                              hipStream_t stream) {
    const float* feat = (const float*)d_in[0];
    char* ws = (char*)d_ws;
    unsigned short* fbf = (unsigned short*)ws;                       // 4 MB bf16
    float* sumexp  = (float*)(ws + 4u * 1024u * 1024u);              // 32 KB
    unsigned int* flg1 = (unsigned int*)(ws + 4u * 1024u * 1024u + 32768u);
    unsigned int* flg2 = flg1 + NBLK;

    k_all<<<NBLK, 256, 0, stream>>>(feat, fbf, sumexp, flg1, flg2, (float*)d_out);
}

// Round 10
// 150.636 us; speedup vs baseline: 1.6633x; 1.6633x over previous
//
#include <hip/hip_runtime.h>
#include <hip/hip_bf16.h>
#include <math.h>

// NT-Xent loss, fully fused single persistent kernel. N=8192 rows, D=256.
// History (totals): R3 131.9 | R5 130.0 | R6 125.0 | R7 124.2 | R9 123.8 |
//   R10 129.9 | R11 191 (LDS CAS-loop atomics) | R12 250 (fused, but the
//   grid barrier had 131072 polling threads + per-thread agent fences ->
//   L2 cache-op storm; work itself unchanged; co-residency PROVEN).
// R13: same fusion, textbook barrier:
//   - centralized sense-reversing epoch barrier, ONE poller per block
//     (tid0 RELEASE fetch_add; last arrival resets cnt + bumps epoch;
//     spinners ACQUIRE-load ONE word; rest of block parks at syncthreads).
//     512 fences total, not 131K.
//   - barrier state in __device__ globals: zero-init at module load,
//     epoch-monotonic => immune to ws re-poison and graph replay.
//   - k_nll deleted: pos-dot (feat-only) moved to phase 0 -> posv[];
//     last-block finisher (2nd device-global counter, ACQ_REL chain) sums
//     posv[i] + log(sumexp[i]) over all rows and stores out[0] directly.
//   - phase 1 = R7's k_sim VERBATIM (best measured k_sim structure).
#define N_ROWS 8192
#define D_DIM  256
#define HALF_N 4096
#define NBLK   512
#define INV_T      14.285714285714286f      // 1/0.07
#define SCALE_LOG2 20.609929155556620f      // log2(e)/0.07
#define NEG_SCALE  -20.609929155556620f
#define EPSV   1e-8f

typedef __attribute__((ext_vector_type(8))) short bf16x8;   // 8 bf16 = 4 VGPR
typedef __attribute__((ext_vector_type(4))) float f32x4;

#define AS1 __attribute__((address_space(1)))
#define AS3 __attribute__((address_space(3)))
#define AGT __HIP_MEMORY_SCOPE_AGENT

__device__ unsigned g_cnt   = 0;   // barrier arrivals (reset by releaser)
__device__ unsigned g_epoch = 0;   // barrier epoch (monotonic forever)
__device__ unsigned g_done  = 0;   // phase-1 completions (monotonic forever)

__device__ inline unsigned short f2bf(float x) {
    unsigned int u = __float_as_uint(x);
    unsigned int r = (u + 0x7fffu + ((u >> 16) & 1u)) >> 16;   // RNE
    return (unsigned short)r;
}

__global__ __launch_bounds__(256, 2) void k_all(const float* __restrict__ feat,
                                                unsigned short* __restrict__ fbf,
                                                float* __restrict__ sumexp,
                                                float* __restrict__ posv,
                                                float* __restrict__ out) {
    __shared__ __align__(16) char Bs[16384];
    __shared__ float red[4];
    __shared__ int lastBlk;
    const int tid  = threadIdx.x;
    const int b    = blockIdx.x;
    const int lane = tid & 63;
    const int w    = tid >> 6;
    const int q    = lane >> 4, l15 = lane & 15;

    // ========== phase 0: normalize 16 rows -> bf16; posv; zero sumexp =====
    #pragma unroll
    for (int r = 0; r < 4; ++r) {
        const int row = b * 16 + w * 4 + r;
        const float4 v = ((const float4*)(feat + row * D_DIM))[lane];
        float ss = v.x*v.x + v.y*v.y + v.z*v.z + v.w*v.w;
        #pragma unroll
        for (int off = 32; off; off >>= 1) ss += __shfl_xor(ss, off);
        const float sc = 1.f / fmaxf(sqrtf(ss), EPSV);
        ushort4 o;
        o.x = f2bf(v.x * sc); o.y = f2bf(v.y * sc);
        o.z = f2bf(v.z * sc); o.w = f2bf(v.w * sc);
        ((ushort4*)(fbf + row * D_DIM))[lane] = o;
    }
    // pos-dot for the same 16 rows (feat-only; independent of sumexp)
    #pragma unroll
    for (int r = 0; r < 4; ++r) {
        const int i  = b * 16 + w * 4 + r;
        const int pc = (i + HALF_N) & (N_ROWS - 1);
        const float4 a = ((const float4*)(feat + i  * D_DIM))[lane];
        const float4 c = ((const float4*)(feat + pc * D_DIM))[lane];
        float dab = a.x*c.x + a.y*c.y + a.z*c.z + a.w*c.w;
        float daa = a.x*a.x + a.y*a.y + a.z*a.z + a.w*a.w;
        float dbb = c.x*c.x + c.y*c.y + c.z*c.z + c.w*c.w;
        #pragma unroll
        for (int off = 32; off; off >>= 1) {
            dab += __shfl_xor(dab, off);
            daa += __shfl_xor(daa, off);
            dbb += __shfl_xor(dbb, off);
        }
        if (lane == 0) {
            const float pos = dab / (fmaxf(sqrtf(daa), EPSV) * fmaxf(sqrtf(dbb), EPSV));
            posv[i] = INV_T - pos * INV_T;
        }
    }
    if (tid < 16) sumexp[b * 16 + tid] = 0.f;

    // ========== grid barrier: epoch, one poller per block =================
    __syncthreads();                               // block's stores issued+drained
    if (tid == 0) {
        const unsigned e = __hip_atomic_load(&g_epoch, __ATOMIC_RELAXED, AGT);
        const unsigned old = __hip_atomic_fetch_add(&g_cnt, 1u, __ATOMIC_ACQ_REL, AGT);
        if (old == NBLK - 1) {
            __hip_atomic_store(&g_cnt, 0u, __ATOMIC_RELAXED, AGT);
            __hip_atomic_fetch_add(&g_epoch, 1u, __ATOMIC_ACQ_REL, AGT);
        } else {
            while (__hip_atomic_load(&g_epoch, __ATOMIC_ACQUIRE, AGT) == e)
                __builtin_amdgcn_s_sleep(8);
        }
    }
    __syncthreads();                               // block observes tid0's acquire

    // ========== phase 1: R7 k_sim body (verbatim) =========================
    {
    int g          = (33 * b) >> 2;                   // first strip
    const int gEnd = (33 * (b + 1)) >> 2;             // one past last

    const int tt0 = g >> 3;
    int rt = (int)((sqrtf(8.f * (float)tt0 + 1.f) - 1.f) * 0.5f);
    while ((rt + 1) * (rt + 2) / 2 <= tt0) ++rt;
    while (rt * (rt + 1) / 2 > tt0) --rt;
    int cs = tt0 - rt * (rt + 1) / 2;
    int jt = g & 7;

#define STAGE(colRow0) do {                                                   \
        const char* Bg_ = (const char*)fbf + (size_t)(colRow0) * 512;         \
        _Pragma("unroll")                                                     \
        for (int i_ = 0; i_ < 4; ++i_) {                                      \
            const int idx_ = i_ * 256 + tid;                                  \
            const int col_ = idx_ >> 5;                                       \
            const int cir_ = idx_ & 31;                                       \
            __builtin_amdgcn_global_load_lds(                                 \
                (const AS1 void*)(Bg_ + col_ * 512 + ((cir_ ^ (col_ & 7)) << 4)), \
                (AS3 void*)(Bs + idx_ * 16), 16, 0, 0);                       \
        }                                                                     \
    } while (0)

    bf16x8 afrag[8][4];
#define LOAD_A(rt_) do {                                                      \
        const int rowBase_ = (rt_) * 256 + w * 64;                            \
        _Pragma("unroll")                                                     \
        for (int t_ = 0; t_ < 8; ++t_)                                        \
            _Pragma("unroll")                                                 \
            for (int ri_ = 0; ri_ < 4; ++ri_)                                 \
                afrag[t_][ri_] = *(const bf16x8*)(fbf                         \
                    + (rowBase_ + ri_*16 + l15) * D_DIM + t_*32 + q*8);       \
    } while (0)

    float rsum[4][4];
#define ZERO_RSUM() do {                                                      \
        _Pragma("unroll")                                                     \
        for (int ri_ = 0; ri_ < 4; ++ri_)                                     \
            _Pragma("unroll")                                                 \
            for (int r_ = 0; r_ < 4; ++r_) rsum[ri_][r_] = 0.f;               \
    } while (0)

#define FLUSH_RSUM(rt_) do {                                                  \
        const int rowBase_ = (rt_) * 256 + w * 64;                            \
        _Pragma("unroll")                                                     \
        for (int ri_ = 0; ri_ < 4; ++ri_)                                     \
            _Pragma("unroll")                                                 \
            for (int r_ = 0; r_ < 4; ++r_) {                                  \
                float s_ = rsum[ri_][r_];                                     \
                s_ += __shfl_xor(s_, 1);                                      \
                s_ += __shfl_xor(s_, 2);                                      \
                s_ += __shfl_xor(s_, 4);                                      \
                s_ += __shfl_xor(s_, 8);                                      \
                if (l15 == 0)                                                 \
                    atomicAdd(&sumexp[rowBase_ + ri_ * 16 + q * 4 + r_], s_); \
            }                                                                 \
    } while (0)

    STAGE(cs * 256 + jt * 32);
    LOAD_A(rt);
    ZERO_RSUM();

    while (true) {
        const int colBase = cs * 256 + jt * 32;
        const bool isDiag = (rt == cs);
        const int rowBase = rt * 256 + w * 64;

        __syncthreads();                           // DMA of strip g drained

        f32x4 acc[4][2];
        #pragma unroll
        for (int ri = 0; ri < 4; ++ri)
            #pragma unroll
            for (int ci = 0; ci < 2; ++ci) acc[ri][ci] = (f32x4){0.f, 0.f, 0.f, 0.f};

        #pragma unroll
        for (int t = 0; t < 8; ++t) {
            bf16x8 bfrag[2];
            #pragma unroll
            for (int ci = 0; ci < 2; ++ci) {
                const int c   = ci * 16 + l15;     // local col 0..31
                const int cir = t * 4 + q;         // k-chunk
                bfrag[ci] = *(const bf16x8*)(Bs + c * 512 + ((cir ^ (c & 7)) << 4));
            }
            #pragma unroll
            for (int ri = 0; ri < 4; ++ri)
                #pragma unroll
                for (int ci = 0; ci < 2; ++ci)
                    acc[ri][ci] = __builtin_amdgcn_mfma_f32_16x16x32_bf16(
                        afrag[t][ri], bfrag[ci], acc[ri][ci], 0, 0, 0);
        }

        const bool more = (g + 1 < gEnd);
        int nrt = rt, ncs = cs, njt = jt + 1;
        if (njt == 8) {
            njt = 0; ncs = cs + 1;
            if (ncs > rt) { nrt = rt + 1; ncs = 0; }
        }

        if (more) {
            __syncthreads();                       // all waves done reading Bs
            STAGE(ncs * 256 + njt * 32);
            if (njt == 0) LOAD_A(nrt);             // reload hides under exp
        }

        if (isDiag) {
            #pragma unroll
            for (int ri = 0; ri < 4; ++ri) {
                const int trow = rowBase + ri * 16;
                #pragma unroll
                for (int ci = 0; ci < 2; ++ci) {
                    const int tcol = colBase + ci * 16;
                    if (trow == tcol) {            // diagonal 16x16 tile
                        #pragma unroll
                        for (int r = 0; r < 4; ++r) {
                            const float e = __builtin_amdgcn_exp2f(
                                __builtin_fmaf(acc[ri][ci][r], SCALE_LOG2, NEG_SCALE));
                            rsum[ri][r] += (q * 4 + r == l15) ? 0.f : e;
                        }
                    } else {
                        #pragma unroll
                        for (int r = 0; r < 4; ++r)
                            rsum[ri][r] += __builtin_amdgcn_exp2f(
                                __builtin_fmaf(acc[ri][ci][r], SCALE_LOG2, NEG_SCALE));
                    }
                }
            }
        } else {
            float csum0 = 0.f, csum1 = 0.f;
            #pragma unroll
            for (int ri = 0; ri < 4; ++ri) {
                #pragma unroll
                for (int r = 0; r < 4; ++r) {
                    const float e0 = __builtin_amdgcn_exp2f(
                        __builtin_fmaf(acc[ri][0][r], SCALE_LOG2, NEG_SCALE));
                    const float e1 = __builtin_amdgcn_exp2f(
                        __builtin_fmaf(acc[ri][1][r], SCALE_LOG2, NEG_SCALE));
                    rsum[ri][r] += e0 + e1;
                    csum0 += e0;
                    csum1 += e1;
                }
            }
            csum0 += __shfl_xor(csum0, 16); csum0 += __shfl_xor(csum0, 32);
            csum1 += __shfl_xor(csum1, 16); csum1 += __shfl_xor(csum1, 32);
            if (q == 0)      atomicAdd(&sumexp[colBase      + l15], csum0);
            else if (q == 1) atomicAdd(&sumexp[colBase + 16 + l15], csum1);
        }

        if (!more) break;
        if (njt == 0) {                            // crossed a tile boundary
            FLUSH_RSUM(rt);
            ZERO_RSUM();
        }
        rt = nrt; cs = ncs; jt = njt; ++g;
    }

    FLUSH_RSUM(rt);
#undef STAGE
#undef LOAD_A
#undef ZERO_RSUM
#undef FLUSH_RSUM
    }

    // ========== last-block finisher: nll sum + mean =======================
    __syncthreads();                               // all waves' atomics drained
    if (tid == 0) {
        const unsigned old = __hip_atomic_fetch_add(&g_done, 1u, __ATOMIC_ACQ_REL, AGT);
        lastBlk = ((old & (NBLK - 1)) == NBLK - 1);
    }
    __syncthreads();
    if (lastBlk) {
        // ACQ_REL add above: all 511 prior blocks' sumexp atomics are
        // complete and caches invalidated -> plain loads are fresh.
        float wsum = 0.f;
        for (int i = tid; i < N_ROWS; i += 256)
            wsum += posv[i] + logf(sumexp[i]);
        #pragma unroll
        for (int off = 32; off; off >>= 1) wsum += __shfl_xor(wsum, off);
        if (lane == 0) red[w] = wsum;
        __syncthreads();
        if (tid == 0)
            out[0] = (red[0] + red[1] + red[2] + red[3]) * (1.f / N_ROWS);
    }
}

extern "C" void kernel_launch(void* const* d_in, const int* in_sizes, int n_in,
                              void* d_out, int out_size, void* d_ws, size_t ws_size,
                              hipStream_t stream) {
    const float* feat = (const float*)d_in[0];
    char* ws = (char*)d_ws;
    unsigned short* fbf = (unsigned short*)ws;                       // 4 MB bf16
    float* sumexp = (float*)(ws + 4u * 1024u * 1024u);               // 32 KB
    float* posv   = (float*)(ws + 4u * 1024u * 1024u + 32768u);      // 32 KB

    k_all<<<NBLK, 256, 0, stream>>>(feat, fbf, sumexp, posv, (float*)d_out);
}

// Round 11
// 107.918 us; speedup vs baseline: 2.3218x; 1.3958x over previous
//
#include <hip/hip_runtime.h>
#include <hip/hip_bf16.h>
#include <math.h>

// NT-Xent loss. N=8192 rows, D=256. Two dispatches:
//   k_prep  : row L2-norm fp32->bf16 (ws), posv[i] = (1-pos_i)/T, zero sumexp
//   k_simfin: R7's k_sim VERBATIM (best measured hot loop) + last-block
//             finisher (device-global arrival counter) stores out[0].
// History: split R9 123.8 best | fused R12 250 (fence storm) | fused R13
//   150.6: barrier fixed (k_all 107) and gaps eliminated, but the hot loop
//   DEGRADED 43->~99 us inside the big kernel: VGPR 116->128 and
//   SQ_LDS_BANK_CONFLICT exactly halved (2.10M->1.08M) = codegen changed.
//   This compiler is fragile about this loop (R4: +16% from one base-ptr
//   change). R14 keeps the hot loop as its own pristine dispatch and only
//   appends a tiny finisher tail; k_nll launch + one gap removed.
#define N_ROWS 8192
#define D_DIM  256
#define HALF_N 4096
#define NBLK   512
#define INV_T      14.285714285714286f      // 1/0.07
#define SCALE_LOG2 20.609929155556620f      // log2(e)/0.07
#define NEG_SCALE  -20.609929155556620f
#define EPSV   1e-8f

typedef __attribute__((ext_vector_type(8))) short bf16x8;   // 8 bf16 = 4 VGPR
typedef __attribute__((ext_vector_type(4))) float f32x4;

#define AS1 __attribute__((address_space(1)))
#define AS3 __attribute__((address_space(3)))
#define AGT __HIP_MEMORY_SCOPE_AGENT

__device__ unsigned g_done = 0;    // k_simfin arrivals (monotonic forever;
                                   // & (NBLK-1) selects last arrival/iter)

__device__ inline unsigned short f2bf(float x) {
    unsigned int u = __float_as_uint(x);
    unsigned int r = (u + 0x7fffu + ((u >> 16) & 1u)) >> 16;   // RNE
    return (unsigned short)r;
}

// ------- kernel 1: normalize -> bf16; posv; zero sumexp --------------------
__global__ __launch_bounds__(256) void k_prep(const float* __restrict__ feat,
                                              unsigned short* __restrict__ fbf,
                                              float* __restrict__ sumexp,
                                              float* __restrict__ posv) {
    const int tid = threadIdx.x, w = tid >> 6, lane = tid & 63;
    const int row = blockIdx.x * 4 + w;              // 2048 blocks * 4 rows
    const int pc  = (row + HALF_N) & (N_ROWS - 1);

    const float4 v = ((const float4*)(feat + row * D_DIM))[lane];
    const float4 c = ((const float4*)(feat + pc  * D_DIM))[lane];
    float ss  = v.x*v.x + v.y*v.y + v.z*v.z + v.w*v.w;   // ||a||^2
    float dab = v.x*c.x + v.y*c.y + v.z*c.z + v.w*c.w;
    float dbb = c.x*c.x + c.y*c.y + c.z*c.z + c.w*c.w;
    #pragma unroll
    for (int off = 32; off; off >>= 1) {
        ss  += __shfl_xor(ss,  off);
        dab += __shfl_xor(dab, off);
        dbb += __shfl_xor(dbb, off);
    }
    const float na = fmaxf(sqrtf(ss), EPSV);
    const float sc = 1.f / na;
    ushort4 o;
    o.x = f2bf(v.x * sc); o.y = f2bf(v.y * sc);
    o.z = f2bf(v.z * sc); o.w = f2bf(v.w * sc);
    ((ushort4*)(fbf + row * D_DIM))[lane] = o;
    if (lane == 0)
        posv[row] = INV_T - (dab / (na * fmaxf(sqrtf(dbb), EPSV))) * INV_T;
    if (tid < 4) sumexp[blockIdx.x * 4 + tid] = 0.f;
}

// ------- kernel 2: R7 k_sim body (verbatim) + last-block finisher ----------
// Work unit = strip (tile tt, jt): 256 rows x 32 cols, tt over the 528
// upper-triangle 256x256 tiles (rt >= cs), jt in [0,8). 4224 strips,
// block b owns [(33b)>>2, (33(b+1))>>2). 4 waves x 64 rows; A in regs
// (128 VGPR). B strip = 16 KB LDS via global_load_lds w=16, XOR-16B-chunk
// swizzle. Off-diag: rsum in regs + csum per strip (shfl + atomicAdd).
// Tail: syncthreads (drain atomics) -> g_done ACQ_REL; last arrival's
// acquire makes all 511 other blocks' sumexp atomics visible (R13-proven),
// sums posv[i]+log(sumexp[i]) over 8192 rows, stores out[0].
__global__ __launch_bounds__(256, 2) void k_simfin(const unsigned short* __restrict__ fbf,
                                                   float* __restrict__ sumexp,
                                                   const float* __restrict__ posv,
                                                   float* __restrict__ out) {
    __shared__ __align__(16) char Bs[16384];
    __shared__ float red[4];
    __shared__ int lastBlk;
    const int tid  = threadIdx.x;
    const int lane = tid & 63;
    const int w    = tid >> 6;
    const int q    = lane >> 4, l15 = lane & 15;

    int g          = (33 * blockIdx.x) >> 2;          // first strip
    const int gEnd = (33 * (blockIdx.x + 1)) >> 2;    // one past last

    const int tt0 = g >> 3;
    int rt = (int)((sqrtf(8.f * (float)tt0 + 1.f) - 1.f) * 0.5f);
    while ((rt + 1) * (rt + 2) / 2 <= tt0) ++rt;
    while (rt * (rt + 1) / 2 > tt0) --rt;
    int cs = tt0 - rt * (rt + 1) / 2;
    int jt = g & 7;

#define STAGE(colRow0) do {                                                   \
        const char* Bg_ = (const char*)fbf + (size_t)(colRow0) * 512;         \
        _Pragma("unroll")                                                     \
        for (int i_ = 0; i_ < 4; ++i_) {                                      \
            const int idx_ = i_ * 256 + tid;                                  \
            const int col_ = idx_ >> 5;                                       \
            const int cir_ = idx_ & 31;                                       \
            __builtin_amdgcn_global_load_lds(                                 \
                (const AS1 void*)(Bg_ + col_ * 512 + ((cir_ ^ (col_ & 7)) << 4)), \
                (AS3 void*)(Bs + idx_ * 16), 16, 0, 0);                       \
        }                                                                     \
    } while (0)

    bf16x8 afrag[8][4];
#define LOAD_A(rt_) do {                                                      \
        const int rowBase_ = (rt_) * 256 + w * 64;                            \
        _Pragma("unroll")                                                     \
        for (int t_ = 0; t_ < 8; ++t_)                                        \
            _Pragma("unroll")                                                 \
            for (int ri_ = 0; ri_ < 4; ++ri_)                                 \
                afrag[t_][ri_] = *(const bf16x8*)(fbf                         \
                    + (rowBase_ + ri_*16 + l15) * D_DIM + t_*32 + q*8);       \
    } while (0)

    float rsum[4][4];
#define ZERO_RSUM() do {                                                      \
        _Pragma("unroll")                                                     \
        for (int ri_ = 0; ri_ < 4; ++ri_)                                     \
            _Pragma("unroll")                                                 \
            for (int r_ = 0; r_ < 4; ++r_) rsum[ri_][r_] = 0.f;               \
    } while (0)

#define FLUSH_RSUM(rt_) do {                                                  \
        const int rowBase_ = (rt_) * 256 + w * 64;                            \
        _Pragma("unroll")                                                     \
        for (int ri_ = 0; ri_ < 4; ++ri_)                                     \
            _Pragma("unroll")                                                 \
            for (int r_ = 0; r_ < 4; ++r_) {                                  \
                float s_ = rsum[ri_][r_];                                     \
                s_ += __shfl_xor(s_, 1);                                      \
                s_ += __shfl_xor(s_, 2);                                      \
                s_ += __shfl_xor(s_, 4);                                      \
                s_ += __shfl_xor(s_, 8);                                      \
                if (l15 == 0)                                                 \
                    atomicAdd(&sumexp[rowBase_ + ri_ * 16 + q * 4 + r_], s_); \
            }                                                                 \
    } while (0)

    STAGE(cs * 256 + jt * 32);
    LOAD_A(rt);
    ZERO_RSUM();

    while (true) {
        const int colBase = cs * 256 + jt * 32;
        const bool isDiag = (rt == cs);
        const int rowBase = rt * 256 + w * 64;

        __syncthreads();                           // DMA of strip g drained

        f32x4 acc[4][2];
        #pragma unroll
        for (int ri = 0; ri < 4; ++ri)
            #pragma unroll
            for (int ci = 0; ci < 2; ++ci) acc[ri][ci] = (f32x4){0.f, 0.f, 0.f, 0.f};

        #pragma unroll
        for (int t = 0; t < 8; ++t) {
            bf16x8 bfrag[2];
            #pragma unroll
            for (int ci = 0; ci < 2; ++ci) {
                const int c   = ci * 16 + l15;     // local col 0..31
                const int cir = t * 4 + q;         // k-chunk
                bfrag[ci] = *(const bf16x8*)(Bs + c * 512 + ((cir ^ (c & 7)) << 4));
            }
            #pragma unroll
            for (int ri = 0; ri < 4; ++ri)
                #pragma unroll
                for (int ci = 0; ci < 2; ++ci)
                    acc[ri][ci] = __builtin_amdgcn_mfma_f32_16x16x32_bf16(
                        afrag[t][ri], bfrag[ci], acc[ri][ci], 0, 0, 0);
        }

        const bool more = (g + 1 < gEnd);
        int nrt = rt, ncs = cs, njt = jt + 1;
        if (njt == 8) {
            njt = 0; ncs = cs + 1;
            if (ncs > rt) { nrt = rt + 1; ncs = 0; }
        }

        if (more) {
            __syncthreads();                       // all waves done reading Bs
            STAGE(ncs * 256 + njt * 32);
            if (njt == 0) LOAD_A(nrt);             // reload hides under exp
        }

        if (isDiag) {
            #pragma unroll
            for (int ri = 0; ri < 4; ++ri) {
                const int trow = rowBase + ri * 16;
                #pragma unroll
                for (int ci = 0; ci < 2; ++ci) {
                    const int tcol = colBase + ci * 16;
                    if (trow == tcol) {            // diagonal 16x16 tile
                        #pragma unroll
                        for (int r = 0; r < 4; ++r) {
                            const float e = __builtin_amdgcn_exp2f(
                                __builtin_fmaf(acc[ri][ci][r], SCALE_LOG2, NEG_SCALE));
                            rsum[ri][r] += (q * 4 + r == l15) ? 0.f : e;
                        }
                    } else {
                        #pragma unroll
                        for (int r = 0; r < 4; ++r)
                            rsum[ri][r] += __builtin_amdgcn_exp2f(
                                __builtin_fmaf(acc[ri][ci][r], SCALE_LOG2, NEG_SCALE));
                    }
                }
            }
        } else {
            float csum0 = 0.f, csum1 = 0.f;
            #pragma unroll
            for (int ri = 0; ri < 4; ++ri) {
                #pragma unroll
                for (int r = 0; r < 4; ++r) {
                    const float e0 = __builtin_amdgcn_exp2f(
                        __builtin_fmaf(acc[ri][0][r], SCALE_LOG2, NEG_SCALE));
                    const float e1 = __builtin_amdgcn_exp2f(
                        __builtin_fmaf(acc[ri][1][r], SCALE_LOG2, NEG_SCALE));
                    rsum[ri][r] += e0 + e1;
                    csum0 += e0;
                    csum1 += e1;
                }
            }
            csum0 += __shfl_xor(csum0, 16); csum0 += __shfl_xor(csum0, 32);
            csum1 += __shfl_xor(csum1, 16); csum1 += __shfl_xor(csum1, 32);
            if (q == 0)      atomicAdd(&sumexp[colBase      + l15], csum0);
            else if (q == 1) atomicAdd(&sumexp[colBase + 16 + l15], csum1);
        }

        if (!more) break;
        if (njt == 0) {                            // crossed a tile boundary
            FLUSH_RSUM(rt);
            ZERO_RSUM();
        }
        rt = nrt; cs = ncs; jt = njt; ++g;
    }

    FLUSH_RSUM(rt);
#undef STAGE
#undef LOAD_A
#undef ZERO_RSUM
#undef FLUSH_RSUM

    // ---- finisher: last arriving block computes the mean -----------------
    __syncthreads();                               // drain this block's atomics
    if (tid == 0) {
        const unsigned old = __hip_atomic_fetch_add(&g_done, 1u, __ATOMIC_ACQ_REL, AGT);
        lastBlk = ((old & (NBLK - 1)) == NBLK - 1);
    }
    __syncthreads();
    if (lastBlk) {
        // acquire above: all 511 prior blocks' sumexp atomics visible; L1
        // invalidated -> plain loads fresh (R13-proven, absmax 0.0).
        float wsum = 0.f;
        for (int i = tid; i < N_ROWS; i += 256)
            wsum += posv[i] + logf(sumexp[i]);
        #pragma unroll
        for (int off = 32; off; off >>= 1) wsum += __shfl_xor(wsum, off);
        if (lane == 0) red[w] = wsum;
        __syncthreads();
        if (tid == 0)
            out[0] = (red[0] + red[1] + red[2] + red[3]) * (1.f / N_ROWS);
    }
}

extern "C" void kernel_launch(void* const* d_in, const int* in_sizes, int n_in,
                              void* d_out, int out_size, void* d_ws, size_t ws_size,
                              hipStream_t stream) {
    const float* feat = (const float*)d_in[0];
    char* ws = (char*)d_ws;
    unsigned short* fbf = (unsigned short*)ws;                       // 4 MB bf16
    float* sumexp = (float*)(ws + 4u * 1024u * 1024u);               // 32 KB
    float* posv   = (float*)(ws + 4u * 1024u * 1024u + 32768u);      // 32 KB

    k_prep  <<<N_ROWS / 4, 256, 0, stream>>>(feat, fbf, sumexp, posv);
    k_simfin<<<NBLK,       256, 0, stream>>>(fbf, sumexp, posv, (float*)d_out);
}